// Round 15
// baseline (327.169 us; speedup 1.0000x reference)
//
#include <hip/hip_runtime.h>
#include <cstdint>
#include <cstddef>

// Problem constants
#define NIMG 32
#define C    128
#define OC   128
#define HW   112
#define HWSZ (HW * HW)       // 12544
#define NTAP 9
// channel-last padded activation buffer: xq[n][114][114][128] int8
#define PHW  114
#define XROW (PHW * C)       // 14592 B per padded row
#define XIMG (PHW * XROW)    // 1,663,488 B per image
#define XQ_BYTES ((size_t)NIMG * XIMG)          // 53,231,616
#define AWQ_BYTES ((size_t)8 * 9 * 2 * 64 * 16) // 147,456

typedef int v4i __attribute__((ext_vector_type(4)));
typedef __attribute__((address_space(1))) const uint32_t* gp_t;
typedef __attribute__((address_space(3))) uint32_t* lp_t;

// sign byte: +1 (0x01) if x>=0 else -1 (0xFF)
__device__ __forceinline__ uint32_t sign_byte(uint32_t bits) {
    return ((bits >> 31) * 0xFEu) ^ 1u;
}

// ---------------------------------------------------------------------------
// Zero the border cells of xq (rows 0,113 full; cols 0,113 for rows 1..112).
__global__ void fill_border(uint8_t* __restrict__ xq) {
    int tid = blockIdx.x * blockDim.x + threadIdx.x;   // 32*3616 total
    int n = tid / 3616, u = tid % 3616;
    size_t off;
    if (u < 912)        off = (size_t)u * 16;                              // top row
    else if (u < 1824)  off = (size_t)113 * XROW + (size_t)(u - 912) * 16; // bottom
    else {
        int j = u - 1824;                 // 0..1791
        int r = (j >> 4) + 1;             // rows 1..112
        int side = (j >> 3) & 1;          // 0=left col, 1=right col
        int cu = j & 7;
        off = (size_t)r * XROW + (size_t)side * (113 * C) + (size_t)cu * 16;
    }
    *(uint4*)(xq + (size_t)n * XIMG + off) = make_uint4(0u, 0u, 0u, 0u);
}

// ---------------------------------------------------------------------------
// Pack x (N,C,112,112) fp32 -> xq channel-last int8 via LDS transpose.
// Block = (n, pair of rows). Load phase: 224 threads x 32 float4 loads.
__global__ __launch_bounds__(256) void pack_x_cl(const float* __restrict__ x,
                                                 uint8_t* __restrict__ xq) {
    __shared__ __align__(16) uint8_t slds[2 * 112 * 144];   // [row][px][c], pad 144
    int n = blockIdx.x / 56, hp = blockIdx.x % 56;
    int h0 = hp * 2;

    int task = threadIdx.x;
    if (task < 224) {
        int r = task / 112, rem = task % 112;
        int word = rem / 28, pxg = rem % 28;      // consecutive lanes -> consecutive px4
        const float* xp = x + ((size_t)(n * C + word * 32)) * HWSZ
                            + (size_t)(h0 + r) * HW + pxg * 4;
        uint32_t dw[4][8];
        #pragma unroll
        for (int i = 0; i < 8; ++i) {
            uint32_t a0 = 0, a1 = 0, a2 = 0, a3 = 0;
            #pragma unroll
            for (int b = 0; b < 4; ++b) {
                float4 v = *reinterpret_cast<const float4*>(xp + (size_t)(i * 4 + b) * HWSZ);
                a0 |= sign_byte(__float_as_uint(v.x)) << (8 * b);
                a1 |= sign_byte(__float_as_uint(v.y)) << (8 * b);
                a2 |= sign_byte(__float_as_uint(v.z)) << (8 * b);
                a3 |= sign_byte(__float_as_uint(v.w)) << (8 * b);
            }
            dw[0][i] = a0; dw[1][i] = a1; dw[2][i] = a2; dw[3][i] = a3;
        }
        #pragma unroll
        for (int j = 0; j < 4; ++j) {
            uint8_t* sp = &slds[(size_t)((r * 112) + pxg * 4 + j) * 144 + word * 32];
            *(uint4*)sp        = make_uint4(dw[j][0], dw[j][1], dw[j][2], dw[j][3]);
            *(uint4*)(sp + 16) = make_uint4(dw[j][4], dw[j][5], dw[j][6], dw[j][7]);
        }
    }
    __syncthreads();

    uint8_t* dst = xq + (size_t)n * XIMG + (size_t)(h0 + 1) * XROW + C;  // col 1
    #pragma unroll
    for (int rep = 0; rep < 7; ++rep) {
        int u = threadIdx.x + rep * 256;          // < 1792
        int row = u / 896, i = u % 896;           // 896*16B = cols 1..112 of one row
        *(uint4*)(dst + (size_t)row * XROW + (size_t)i * 16) =
            *(const uint4*)&slds[(size_t)(row * 112 + (i >> 3)) * 144 + (i & 7) * 16];
    }
}

// ---------------------------------------------------------------------------
// Build A-fragments for mfma_i32_16x16x64_i8 (R6-proven layout):
// awq[f][lane][16B], f = ((o16*9 + tap)*2 + ks); lane l: row m=l&15, k=(l>>4)*16+j.
__global__ void pack_w_frag(const float* __restrict__ w, uint32_t* __restrict__ awq) {
    int tid = blockIdx.x * blockDim.x + threadIdx.x;   // 36864 dwords
    int d = tid & 3, l = (tid >> 2) & 63, f = tid >> 8;
    int ks = f & 1, tf = f >> 1;
    int tap = tf % 9, o16 = tf / 9;
    int o = o16 * 16 + (l & 15);
    int cb = ks * 64 + ((l >> 4) & 3) * 16 + d * 4;
    uint32_t acc = 0;
    #pragma unroll
    for (int jj = 0; jj < 4; ++jj) {
        uint32_t bits = __float_as_uint(w[(size_t)(o * C + cb + jj) * NTAP + tap]);
        acc |= sign_byte(bits) << (8 * jj);
    }
    awq[tid] = acc;
}

// ---------------------------------------------------------------------------
// Binary conv as int8 implicit GEMM, staging via global_load_lds DMA.
// Block = (n, h), XCD-swizzled.  LDS is LINEAR (DMA constraint); the XOR
// bank-swizzle is applied to the SOURCE address instead (involution:
// u = v ^ ((v>>3)%114 & 7)), so the R6-proven swizzled compute reads are
// unchanged.  DMA requests don't occupy VGPR results -> unbounded
// outstanding-ness; 3 blocks/CU (LDS 45056B) x 4 waves = 12 waves/CU.
__global__ __launch_bounds__(256, 3) void bconv_mfma(const uint8_t* __restrict__ xq,
                                                     const uint8_t* __restrict__ awq,
                                                     float* __restrict__ out) {
    __shared__ __align__(16) uint8_t sxq[2816 * 16];   // 45056 B (43776 used + pad)
    int bid = blockIdx.x;                              // 3584 = 8 * 448, bijective
    int swz = (bid & 7) * 448 + (bid >> 3);
    int n = swz / HW, h = swz % HW;

    int t = threadIdx.x;
    int wv = t >> 6, l = t & 63;

    // resident A fragments: 2 o-tiles x 9 taps x 2 k-slices (144 AGPR)
    v4i A[2][9][2];
    #pragma unroll
    for (int ot = 0; ot < 2; ++ot)
        #pragma unroll
        for (int tap = 0; tap < 9; ++tap)
            #pragma unroll
            for (int ks = 0; ks < 2; ++ks) {
                int f = ((wv * 2 + ot) * 9 + tap) * 2 + ks;
                A[ot][tap][ks] = *(const v4i*)(awq + (size_t)f * 1024 + (size_t)l * 16);
            }

    // ---- staging: 2736 16B cells (3 padded rows) via global_load_lds -------
    const uint8_t* src = xq + (size_t)n * XIMG + (size_t)h * XROW;
    #pragma unroll
    for (int k = 0; k < 11; ++k) {
        int v = k * 256 + t;                           // LDS cell (linear)
        if (v < 2736) {
            int s = ((v >> 3) % PHW) & 7;              // bank-swizzle bits
            int u = v ^ s;                             // pre-swizzled source cell
            __builtin_amdgcn_global_load_lds(
                (gp_t)(const void*)(src + (size_t)u * 16),
                (lp_t)(void*)&sxq[(size_t)(k * 256 + (t & 192)) * 16],
                16, 0, 0);
        }
    }
    __syncthreads();

    // ---- compute: 7 N-tiles of 16 px, 18 ds_read_b128 + 36 MFMA each -------
    int l15 = l & 15, lk = (l >> 4) * 16;
    float* outb = out + ((size_t)n * OC + wv * 32) * HWSZ + h * HW;

    for (int nt = 0; nt < 7; ++nt) {
        int w0 = nt * 16;
        int ad[3][2];
        #pragma unroll
        for (int kw = 0; kw < 3; ++kw) {
            int pix = w0 + l15 + kw;                   // padded col, always in-bounds
            int x4 = (pix & 7) << 4;
            int base = pix * C;
            ad[kw][0] = base + (lk ^ x4);
            ad[kw][1] = base + ((lk + 64) ^ x4);
        }
        v4i acc0 = {0, 0, 0, 0}, acc1 = {0, 0, 0, 0};
        #pragma unroll
        for (int kh = 0; kh < 3; ++kh)
            #pragma unroll
            for (int kw = 0; kw < 3; ++kw)
                #pragma unroll
                for (int ks = 0; ks < 2; ++ks) {
                    v4i b = *(const v4i*)&sxq[kh * XROW + ad[kw][ks]];
                    acc0 = __builtin_amdgcn_mfma_i32_16x16x64_i8(
                               A[0][kh * 3 + kw][ks], b, acc0, 0, 0, 0);
                    acc1 = __builtin_amdgcn_mfma_i32_16x16x64_i8(
                               A[1][kh * 3 + kw][ks], b, acc1, 0, 0, 0);
                }
        #pragma unroll
        for (int r = 0; r < 4; ++r) {
            int oof = ((l >> 4) << 2) + r;             // D: col=l&15, row=(l>>4)*4+r
            outb[(size_t)oof * HWSZ + w0 + l15]        = (float)acc0[r];
            outb[(size_t)(oof + 16) * HWSZ + w0 + l15] = (float)acc1[r];
        }
    }
}

// ===========================================================================
extern "C" void kernel_launch(void* const* d_in, const int* in_sizes, int n_in,
                              void* d_out, int out_size, void* d_ws, size_t ws_size,
                              hipStream_t stream) {
    const float* x   = (const float*)d_in[0];
    const float* wts = (const float*)d_in[1];
    float* out = (float*)d_out;
    uint8_t* ws = (uint8_t*)d_ws;

    uint8_t*  xq  = ws;
    uint32_t* awq = (uint32_t*)(ws + XQ_BYTES);

    hipLaunchKernelGGL(fill_border, dim3(NIMG * 3616 / 256), dim3(256), 0, stream, xq);
    hipLaunchKernelGGL(pack_w_frag, dim3(144), dim3(256), 0, stream, wts, awq);
    hipLaunchKernelGGL(pack_x_cl, dim3(NIMG * 56), dim3(256), 0, stream, x, xq);
    hipLaunchKernelGGL(bconv_mfma, dim3(NIMG * HW), dim3(256), 0, stream,
                       xq, (const uint8_t*)awq, out);
}